// Round 7
// baseline (3804.331 us; speedup 1.0000x reference)
//
#include <hip/hip_runtime.h>

typedef unsigned short u16;
typedef unsigned int u32;
typedef _Float16 f16;
typedef __attribute__((ext_vector_type(8))) _Float16 f16x8;
typedef __attribute__((ext_vector_type(4))) float f32x4;

#define NN 40000
#define EE 100000
#define DD 64
#define BB 256
#define SXS 68   // padded LDS stride: kg-groups land 16 banks apart (2-way = free)
#define EPB 64   // edges per block; 4 waves = 2 edge-groups x 2 k-halves

__device__ inline float sigmoidf_(float x){
    return 1.f / (1.f + __expf(-x));
}
__device__ inline float tanhf_(float x){
    x = fmaxf(fminf(x, 15.f), -15.f);
    float e = __expf(2.f * x);
    return (e - 1.f) / (e + 1.f);
}

// ---------------- prep: transposes, f16 convert, eff bias, offsets -----------
__global__ __launch_bounds__(256) void prep_kernel(
    const float* __restrict__ en_w2, f16* __restrict__ w2h,
    const float* __restrict__ gru_wih, const float* __restrict__ gru_whh,
    float* __restrict__ wTs,
    const float* __restrict__ ls_wih0, const float* __restrict__ ls_wih12,
    const float* __restrict__ ls_whh, float* __restrict__ lsT,
    const float* __restrict__ lin3_w, float* __restrict__ lin3T,
    const float* __restrict__ gru_bih, const float* __restrict__ conv_b,
    float* __restrict__ effb,
    const int* __restrict__ node_graph, int* __restrict__ offs)
{
    int i = blockIdx.x * 256 + threadIdx.x;
    if (i < 524288){
        w2h[i] = (f16)en_w2[i];
        return;
    }
    i -= 524288;
    if (i < 24576){
        int which = i / 12288, r = i % 12288;
        int d = r / 192, g = r % 192;
        const float* W = which ? gru_whh : gru_wih;
        wTs[which * 12288 + d * 192 + g] = W[g * 64 + d];
        return;
    }
    i -= 24576;
    if (i < 114688){
        float v;
        if (i < 32768){
            int d = i >> 8, g = i & 255;
            v = ls_wih0[g * 128 + d];
        } else if (i < 65536){
            int j = i - 32768;
            int l = j >> 14, r = j & 16383;
            int d = r >> 8, g = r & 255;
            v = ls_wih12[l * 16384 + g * 64 + d];
        } else {
            int j = i - 65536;
            int l = j >> 14, r = j & 16383;
            int d = r >> 8, g = r & 255;
            v = ls_whh[l * 16384 + g * 64 + d];
        }
        lsT[i] = v;
        return;
    }
    i -= 114688;
    if (i < 16384){
        int ii = i >> 7, jj = i & 127;
        lin3T[i] = lin3_w[jj * 128 + ii];
        return;
    }
    i -= 16384;
    if (i < 192){
        float b = gru_bih[i];
        #pragma unroll
        for (int d = 0; d < 64; d++) b += gru_wih[i * 64 + d] * conv_b[d];
        effb[i] = b;
        return;
    }
    i -= 192;
    if (i <= 256){
        int lo = 0, hi = NN;
        while (lo < hi){
            int mid = (lo + hi) >> 1;
            if (node_graph[mid] < i) lo = mid + 1; else hi = mid;
        }
        offs[i] = lo;
        return;
    }
}

// ---------------- lin0: out = n_feat @ lin0_w^T + b  (writes h in d_out) -----
__global__ __launch_bounds__(256) void lin0_kernel(
    const float* __restrict__ nf, const float* __restrict__ w,
    const float* __restrict__ b, float* __restrict__ out)
{
    int tid = blockIdx.x * 256 + threadIdx.x;
    int n = tid >> 6, d = tid & 63;
    if (n >= NN) return;
    float acc = b[d];
    const float* nr = nf + (size_t)n * 23;
    const float* wr = w + d * 23;
    #pragma unroll
    for (int j = 0; j < 23; j++) acc = fmaf(nr[j], wr[j], acc);
    out[(size_t)n * 64 + d] = acc;
}

// ---------------- edge hidden: relu(e_feat @ w1^T + b1) -> f16 hi/lo ---------
__global__ __launch_bounds__(256) void edge_hidden_kernel(
    const float* __restrict__ ef, const float* __restrict__ w1,
    const float* __restrict__ b1, f16* __restrict__ hidh, f16* __restrict__ hidl)
{
    int tid = blockIdx.x * 256 + threadIdx.x;
    int e = tid >> 7, k = tid & 127;
    if (e >= EE) return;
    float acc = b1[k];
    const float* er = ef + (size_t)e * 19;
    const float* wr = w1 + k * 19;
    #pragma unroll
    for (int j = 0; j < 19; j++) acc = fmaf(er[j], wr[j], acc);
    acc = fmaxf(acc, 0.f);
    f16 hi = (f16)acc;
    f16 lo = (f16)(acc - (float)hi);
    hidh[(size_t)e * 128 + k] = hi;
    hidl[(size_t)e * 128 + k] = lo;
}

// ---------------- fused msg: ew tile stays in MFMA accs, never stored --------
// msg[e,f] = sum_d x[e,d] * ( sum_k u[e,k]*W2[d*64+f,k] + b2[d*64+f] )
// block = 64 edges, 4 waves: wave = (edge-group eg of 32, k-half kh of 64).
// Working set engineered under the compiler's observed ~128-VGPR clamp:
// A hi+lo 32 + msg 32 + B 32 + xv 8 + addr ~ 120 -> fully register-resident.
// 1563 blocks x 4 waves = 6.1 waves/SIMD hides load latency by TLP.
// b2 C-in only on kh=0 waves; halves merge via the atomicAdd scatter.
__global__ __launch_bounds__(256) void msg_fused_kernel(
    const float* __restrict__ h, const f16* __restrict__ hidh,
    const f16* __restrict__ hidl, const f16* __restrict__ w2h,
    const float* __restrict__ b2, const int* __restrict__ src,
    const int* __restrict__ dst, float* __restrict__ m)
{
    __shared__ float s_x[EPB * SXS];
    __shared__ int s_dst[EPB];
    const int t = threadIdx.x;
    const int base = blockIdx.x * EPB;
    for (int i = t; i < EPB * 64; i += 256){
        int el = i >> 6, f = i & 63;
        int e = base + el;
        float v = 0.f;
        if (e < EE) v = h[(size_t)src[e] * 64 + f];
        s_x[el * SXS + f] = v;
    }
    if (t < EPB){
        int e = base + t;
        s_dst[t] = (e < EE) ? dst[e] : -1;
    }
    __syncthreads();

    const int lane = t & 63;
    const int wid = t >> 6;
    const int eg = wid >> 1;           // edge group (32 edges)
    const int kh = wid & 1;            // k half (64 of 128)
    const int r16 = lane & 15;
    const int kg = lane >> 4;
    const int we = eg * 32;            // wave's local edge base

    // A fragments (hi and lo) for this wave's k-half: 8 frags = 32 VGPR
    f16x8 ah[2][2], al[2][2];
    #pragma unroll
    for (int mt = 0; mt < 2; mt++){
        int e = base + we + mt * 16 + r16;
        #pragma unroll
        for (int ks = 0; ks < 2; ks++){
            int koff = kh * 64 + ks * 32 + kg * 8;
            if (e < EE){
                ah[mt][ks] = *(const f16x8*)(hidh + (size_t)e * 128 + koff);
                al[mt][ks] = *(const f16x8*)(hidl + (size_t)e * 128 + koff);
            } else {
                f16x8 z = {0,0,0,0,0,0,0,0};
                ah[mt][ks] = z; al[mt][ks] = z;
            }
        }
    }

    f32x4 msg[2][4];                   // [mt][ft]: 32 VGPR
    #pragma unroll
    for (int a = 0; a < 2; a++)
        #pragma unroll
        for (int b = 0; b < 4; b++){
            f32x4 z = {0.f, 0.f, 0.f, 0.f};
            msg[a][b] = z;
        }

    // per-lane B base: col = d*64 + ft*16 + r16 -> addr = base + d*8192 + ft*2048
    const f16* __restrict__ bbase = w2h + (size_t)r16 * 128 + kh * 64 + kg * 8;
    const float* __restrict__ b2base = b2 + r16;

    for (int d = 0; d < 64; d++){
        f32x4 xv[2];
        #pragma unroll
        for (int mt = 0; mt < 2; mt++)
            #pragma unroll
            for (int r = 0; r < 4; r++)
                xv[mt][r] = s_x[(we + mt * 16 + kg * 4 + r) * SXS + d];
        const f16* bd = bbase + d * 8192;
        // batch all 8 B loads before the MFMA block
        f16x8 bf[4][2];
        #pragma unroll
        for (int ft = 0; ft < 4; ft++){
            bf[ft][0] = *(const f16x8*)(bd + ft * 2048);
            bf[ft][1] = *(const f16x8*)(bd + ft * 2048 + 32);
        }
        const float* b2d = b2base + d * 64;
        #pragma unroll
        for (int ft = 0; ft < 4; ft++){
            float b2v = (kh == 0) ? b2d[ft * 16] : 0.f;
            #pragma unroll
            for (int mt = 0; mt < 2; mt++){
                f32x4 acc = {b2v, b2v, b2v, b2v};
                acc = __builtin_amdgcn_mfma_f32_16x16x32_f16(ah[mt][0], bf[ft][0], acc, 0, 0, 0);
                acc = __builtin_amdgcn_mfma_f32_16x16x32_f16(ah[mt][1], bf[ft][1], acc, 0, 0, 0);
                acc = __builtin_amdgcn_mfma_f32_16x16x32_f16(al[mt][0], bf[ft][0], acc, 0, 0, 0);
                acc = __builtin_amdgcn_mfma_f32_16x16x32_f16(al[mt][1], bf[ft][1], acc, 0, 0, 0);
                msg[mt][ft] = xv[mt] * acc + msg[mt][ft];
            }
        }
    }
    // scatter-add into m[dst[e], f]
    #pragma unroll
    for (int mt = 0; mt < 2; mt++){
        #pragma unroll
        for (int r = 0; r < 4; r++){
            int el = we + mt * 16 + kg * 4 + r;
            int dt = s_dst[el];
            if (dt >= 0){
                #pragma unroll
                for (int ft = 0; ft < 4; ft++)
                    atomicAdd(&m[(size_t)dt * 64 + ft * 16 + r16], msg[mt][ft][r]);
            }
        }
    }
}

// ---------------- GRU GEMM: G[n,g] = bias[g] + sum_d X[n,d]*wT[d,g], g<192 ---
__global__ __launch_bounds__(128) void gru_gemm_kernel(
    const float* __restrict__ m, const float* __restrict__ h,
    const float* __restrict__ wTs, const float* __restrict__ effb,
    const float* __restrict__ bhh,
    float* __restrict__ gi, float* __restrict__ gh)
{
    const int which = blockIdx.y;
    const float* __restrict__ X = which ? h : m;
    const float* __restrict__ wT = wTs + which * (64 * 192);
    const float* __restrict__ bias = which ? bhh : effb;
    float* __restrict__ G = which ? gh : gi;
    const int n0 = blockIdx.x * 128;
    const int t = threadIdx.x;
    __shared__ float s_x[128][65];
    __shared__ float s_b[128][17];
    for (int i = t; i < 128 * 64; i += 128){
        int nn = i >> 6, d = i & 63;
        int n = n0 + nn;
        s_x[nn][d] = (n < NN) ? X[(size_t)n * 64 + d] : 0.f;
    }
    __syncthreads();
    for (int gc = 0; gc < 12; gc++){
        float acc[16];
        #pragma unroll
        for (int j = 0; j < 16; j++) acc[j] = bias[gc * 16 + j];
        #pragma unroll 4
        for (int d = 0; d < 64; d++){
            float xv = s_x[t][d];
            const float* wr = wT + d * 192 + gc * 16;
            #pragma unroll
            for (int j = 0; j < 16; j++) acc[j] = fmaf(xv, wr[j], acc[j]);
        }
        #pragma unroll
        for (int j = 0; j < 16; j++) s_b[t][j] = acc[j];
        __syncthreads();
        for (int i = t; i < 128 * 16; i += 128){
            int nn = i >> 4, j = i & 15;
            int n = n0 + nn;
            if (n < NN) G[(size_t)n * 192 + gc * 16 + j] = s_b[nn][j];
        }
        __syncthreads();
    }
}

// ---------------- GRU gates: h' = (1-z)*n + z*h --------------------------
__global__ __launch_bounds__(256) void gru_gate_kernel(
    const float* __restrict__ gi, const float* __restrict__ gh,
    float* __restrict__ h)
{
    int tid = blockIdx.x * 256 + threadIdx.x;
    int n = tid >> 6, f = tid & 63;
    if (n >= NN) return;
    size_t b = (size_t)n * 192;
    float ir = gi[b + f], iz = gi[b + 64 + f], inn = gi[b + 128 + f];
    float hr = gh[b + f], hz = gh[b + 64 + f], hn = gh[b + 128 + f];
    float r = sigmoidf_(ir + hr);
    float z = sigmoidf_(iz + hz);
    float nv = tanhf_(inn + r * hn);
    size_t hb = (size_t)n * 64 + f;
    float hv = h[hb];
    h[hb] = (1.f - z) * nv + z * hv;
}

// ---------------- Set2Set + final projection: one block per graph ------------
__global__ __launch_bounds__(256) void set2set_kernel(
    const float* __restrict__ out, const int* __restrict__ offs,
    const float* __restrict__ lsT, const float* __restrict__ ls_bih,
    const float* __restrict__ ls_bhh, const float* __restrict__ lin3T,
    const float* __restrict__ lin3_b, const float* __restrict__ pred_w,
    const float* __restrict__ pred_b, float* __restrict__ e_ws,
    float* __restrict__ pred_out)
{
    int g = blockIdx.x;
    int t = threadIdx.x;
    int ln = t >> 6, d = t & 63;
    __shared__ float s_qstar[128], s_h[3][64], s_c[3][64], s_g[256];
    __shared__ float s_r[4][64], s_red[4], s_wsum[4], s_y[128];
    if (t < 128) s_qstar[t] = 0.f;
    if (t < 192){ s_h[t / 64][t % 64] = 0.f; s_c[t / 64][t % 64] = 0.f; }
    int ns = offs[g], ne = offs[g + 1];
    __syncthreads();

    for (int it = 0; it < 6; it++){
        for (int l = 0; l < 3; l++){
            const float* xv = (l == 0) ? s_qstar : s_h[l - 1];
            int xdim = (l == 0) ? 128 : 64;
            const float* wxT = lsT + ((l == 0) ? 0 : (32768 + (l - 1) * 16384));
            const float* whT = lsT + 65536 + l * 16384;
            float acc = ls_bih[l * 256 + t] + ls_bhh[l * 256 + t];
            for (int j = 0; j < xdim; j++) acc = fmaf(xv[j], wxT[j * 256 + t], acc);
            #pragma unroll 4
            for (int j = 0; j < 64; j++) acc = fmaf(s_h[l][j], whT[j * 256 + t], acc);
            __syncthreads();
            s_g[t] = acc;
            __syncthreads();
            if (t < 64){
                float iv = s_g[t], fv = s_g[64 + t], gv = s_g[128 + t], ov = s_g[192 + t];
                float c2 = sigmoidf_(fv) * s_c[l][t] + sigmoidf_(iv) * tanhf_(gv);
                float h2 = sigmoidf_(ov) * tanhf_(c2);
                s_c[l][t] = c2; s_h[l][t] = h2;
            }
            __syncthreads();
        }
        float wmax = -3.4e38f;
        for (int n = ns + ln; n < ne; n += 4){
            float p = out[(size_t)n * 64 + d] * s_h[2][d];
            #pragma unroll
            for (int o = 1; o < 64; o <<= 1) p += __shfl_xor(p, o);
            if (d == 0) e_ws[n] = p;
            wmax = fmaxf(wmax, p);
        }
        if (d == 0) s_red[ln] = wmax;
        __syncthreads();
        float gmax = fmaxf(fmaxf(s_red[0], s_red[1]), fmaxf(s_red[2], s_red[3]));
        float wsum = 0.f, racc = 0.f;
        for (int n = ns + ln; n < ne; n += 4){
            float w = __expf(e_ws[n] - gmax);
            wsum += w;
            racc = fmaf(w, out[(size_t)n * 64 + d], racc);
        }
        s_r[ln][d] = racc;
        if (d == 0) s_wsum[ln] = wsum;
        __syncthreads();
        if (t < 64){
            float gsum = s_wsum[0] + s_wsum[1] + s_wsum[2] + s_wsum[3];
            float ro = s_r[0][t] + s_r[1][t] + s_r[2][t] + s_r[3][t];
            ro = (gsum > 0.f) ? ro / gsum : 0.f;
            s_qstar[t] = s_h[2][t];
            s_qstar[64 + t] = ro;
        }
        __syncthreads();
    }
    if (t < 128){
        float acc = lin3_b[t];
        #pragma unroll 4
        for (int i = 0; i < 128; i++) acc = fmaf(s_qstar[i], lin3T[i * 128 + t], acc);
        s_y[t] = fmaxf(acc, 0.f);
    }
    __syncthreads();
    if (t < 64){
        float p = s_y[t] * pred_w[t] + s_y[64 + t] * pred_w[64 + t];
        #pragma unroll
        for (int o = 1; o < 64; o <<= 1) p += __shfl_xor(p, o);
        if (t == 0) pred_out[g] = p + pred_b[0];
    }
}

extern "C" void kernel_launch(void* const* d_in, const int* in_sizes, int n_in,
                              void* d_out, int out_size, void* d_ws, size_t ws_size,
                              hipStream_t stream)
{
    (void)in_sizes; (void)n_in; (void)out_size; (void)ws_size;
    const float* n_feat  = (const float*)d_in[0];
    const float* e_feat  = (const float*)d_in[1];
    const int*   src     = (const int*)d_in[2];
    const int*   dst     = (const int*)d_in[3];
    const int*   node_graph = (const int*)d_in[4];
    const float* lin0_w  = (const float*)d_in[6];
    const float* lin0_b  = (const float*)d_in[7];
    const float* en_w1   = (const float*)d_in[8];
    const float* en_b1   = (const float*)d_in[9];
    const float* en_w2   = (const float*)d_in[10];
    const float* en_b2   = (const float*)d_in[11];
    const float* conv_b  = (const float*)d_in[12];
    const float* gru_wih = (const float*)d_in[13];
    const float* gru_whh = (const float*)d_in[14];
    const float* gru_bih = (const float*)d_in[15];
    const float* gru_bhh = (const float*)d_in[16];
    const float* ls_wih0 = (const float*)d_in[17];
    const float* ls_wih12= (const float*)d_in[18];
    const float* ls_whh  = (const float*)d_in[19];
    const float* ls_bih  = (const float*)d_in[20];
    const float* ls_bhh  = (const float*)d_in[21];
    const float* lin3_w  = (const float*)d_in[22];
    const float* lin3_b  = (const float*)d_in[23];
    const float* pred_w  = (const float*)d_in[24];
    const float* pred_b  = (const float*)d_in[25];

    float* h = (float*)d_out;                       // N x 64 (also "out")
    float* pred_out = (float*)d_out + (size_t)NN * 64;

    char* ws = (char*)d_ws;
    f16*   hidh  = (f16*)(ws + 0);                  // 25,600,000
    f16*   hidl  = (f16*)(ws + 25600000);           // 25,600,000
    float* m     = (float*)(ws + 51200000);         // 10,240,000
    float* gi    = (float*)(ws + 61440000);         // 30,720,000
    float* gh    = (float*)(ws + 92160000);         // 30,720,000
    f16*   w2h   = (f16*)(ws + 122880000);          //  1,048,576
    float* wTs   = (float*)(ws + 123928576);        //     98,304
    float* lsT   = (float*)(ws + 124026880);        //    458,752
    float* lin3T = (float*)(ws + 124485632);        //     65,536
    float* effb  = (float*)(ws + 124551168);        //        768
    float* e_ws  = (float*)(ws + 124551936);        //    160,000
    int*   offs  = (int*)(ws + 124711936);          //      1,028

    prep_kernel<<<2658, 256, 0, stream>>>(en_w2, w2h, gru_wih, gru_whh, wTs,
                                          ls_wih0, ls_wih12, ls_whh, lsT,
                                          lin3_w, lin3T, gru_bih, conv_b, effb,
                                          node_graph, offs);
    lin0_kernel<<<(NN * 64) / 256, 256, 0, stream>>>(n_feat, lin0_w, lin0_b, h);
    edge_hidden_kernel<<<(EE * 128) / 256, 256, 0, stream>>>(e_feat, en_w1, en_b1, hidh, hidl);

    for (int step = 0; step < 6; step++){
        hipMemsetAsync(m, 0, (size_t)NN * 64 * sizeof(float), stream);
        msg_fused_kernel<<<(EE + EPB - 1) / EPB, 256, 0, stream>>>(h, hidh, hidl, w2h,
                                                                   en_b2, src, dst, m);
        dim3 gg((NN + 127) / 128, 2);
        gru_gemm_kernel<<<gg, 128, 0, stream>>>(m, h, wTs, effb, gru_bhh, gi, gh);
        gru_gate_kernel<<<(NN * 64) / 256, 256, 0, stream>>>(gi, gh, h);
    }

    set2set_kernel<<<BB, 256, 0, stream>>>(h, offs, lsT, ls_bih, ls_bhh,
                                           lin3T, lin3_b, pred_w, pred_b,
                                           e_ws, pred_out);
}

// Round 8
// 3391.484 us; speedup vs baseline: 1.1217x; 1.1217x over previous
//
#include <hip/hip_runtime.h>

typedef unsigned short u16;
typedef unsigned int u32;
typedef _Float16 f16;
typedef __attribute__((ext_vector_type(8))) _Float16 f16x8;
typedef __attribute__((ext_vector_type(4))) float f32x4;

#define NN 40000
#define EE 100000
#define DD 64
#define BB 256
#define SXS 68   // padded LDS stride: kg-groups land 16 banks apart (2-way = free)
#define EPB 256  // edges per block (4 waves x 64 edges, full K per wave)

__device__ inline float sigmoidf_(float x){
    return 1.f / (1.f + __expf(-x));
}
__device__ inline float tanhf_(float x){
    x = fmaxf(fminf(x, 15.f), -15.f);
    float e = __expf(2.f * x);
    return (e - 1.f) / (e + 1.f);
}

// ---------------- prep: transposes, f16 convert, eff bias, offsets -----------
__global__ __launch_bounds__(256) void prep_kernel(
    const float* __restrict__ en_w2, f16* __restrict__ w2h,
    const float* __restrict__ gru_wih, const float* __restrict__ gru_whh,
    float* __restrict__ wTs,
    const float* __restrict__ ls_wih0, const float* __restrict__ ls_wih12,
    const float* __restrict__ ls_whh, float* __restrict__ lsT,
    const float* __restrict__ lin3_w, float* __restrict__ lin3T,
    const float* __restrict__ gru_bih, const float* __restrict__ conv_b,
    float* __restrict__ effb,
    const int* __restrict__ node_graph, int* __restrict__ offs)
{
    int i = blockIdx.x * 256 + threadIdx.x;
    if (i < 524288){
        w2h[i] = (f16)en_w2[i];
        return;
    }
    i -= 524288;
    if (i < 24576){
        int which = i / 12288, r = i % 12288;
        int d = r / 192, g = r % 192;
        const float* W = which ? gru_whh : gru_wih;
        wTs[which * 12288 + d * 192 + g] = W[g * 64 + d];
        return;
    }
    i -= 24576;
    if (i < 114688){
        float v;
        if (i < 32768){
            int d = i >> 8, g = i & 255;
            v = ls_wih0[g * 128 + d];
        } else if (i < 65536){
            int j = i - 32768;
            int l = j >> 14, r = j & 16383;
            int d = r >> 8, g = r & 255;
            v = ls_wih12[l * 16384 + g * 64 + d];
        } else {
            int j = i - 65536;
            int l = j >> 14, r = j & 16383;
            int d = r >> 8, g = r & 255;
            v = ls_whh[l * 16384 + g * 64 + d];
        }
        lsT[i] = v;
        return;
    }
    i -= 114688;
    if (i < 16384){
        int ii = i >> 7, jj = i & 127;
        lin3T[i] = lin3_w[jj * 128 + ii];
        return;
    }
    i -= 16384;
    if (i < 192){
        float b = gru_bih[i];
        #pragma unroll
        for (int d = 0; d < 64; d++) b += gru_wih[i * 64 + d] * conv_b[d];
        effb[i] = b;
        return;
    }
    i -= 192;
    if (i <= 256){
        int lo = 0, hi = NN;
        while (lo < hi){
            int mid = (lo + hi) >> 1;
            if (node_graph[mid] < i) lo = mid + 1; else hi = mid;
        }
        offs[i] = lo;
        return;
    }
}

// ---------------- lin0: out = n_feat @ lin0_w^T + b  (writes h in d_out) -----
__global__ __launch_bounds__(256) void lin0_kernel(
    const float* __restrict__ nf, const float* __restrict__ w,
    const float* __restrict__ b, float* __restrict__ out)
{
    int tid = blockIdx.x * 256 + threadIdx.x;
    int n = tid >> 6, d = tid & 63;
    if (n >= NN) return;
    float acc = b[d];
    const float* nr = nf + (size_t)n * 23;
    const float* wr = w + d * 23;
    #pragma unroll
    for (int j = 0; j < 23; j++) acc = fmaf(nr[j], wr[j], acc);
    out[(size_t)n * 64 + d] = acc;
}

// ---------------- edge hidden: relu(e_feat @ w1^T + b1) -> f16 hi/lo ---------
__global__ __launch_bounds__(256) void edge_hidden_kernel(
    const float* __restrict__ ef, const float* __restrict__ w1,
    const float* __restrict__ b1, f16* __restrict__ hidh, f16* __restrict__ hidl)
{
    int tid = blockIdx.x * 256 + threadIdx.x;
    int e = tid >> 7, k = tid & 127;
    if (e >= EE) return;
    float acc = b1[k];
    const float* er = ef + (size_t)e * 19;
    const float* wr = w1 + k * 19;
    #pragma unroll
    for (int j = 0; j < 19; j++) acc = fmaf(er[j], wr[j], acc);
    acc = fmaxf(acc, 0.f);
    f16 hi = (f16)acc;
    f16 lo = (f16)(acc - (float)hi);
    hidh[(size_t)e * 128 + k] = hi;
    hidl[(size_t)e * 128 + k] = lo;
}

// ---------------- fused msg: ew tile stays in MFMA accs, never stored --------
// msg[e,f] = sum_d x[e,d] * ( sum_k u[e,k]*W2[d*64+f,k] + b2[d*64+f] )
// block = 256 edges (4 waves x 64 edges, full K). amdgpu_waves_per_eu(1,2)
// pins the scheduler's occupancy target at 2 waves/EU (LDS already caps us
// there) so A hi+lo (128 VGPR) + msg accs (64) stay live with no L1 reloads
// -- launch_bounds(256,2) alone let the scheduler target 4 waves and clamp
// to 124 VGPR (R4/R6).
__global__ __launch_bounds__(256)
__attribute__((amdgpu_waves_per_eu(1, 2)))
void msg_fused_kernel(
    const float* __restrict__ h, const f16* __restrict__ hidh,
    const f16* __restrict__ hidl, const f16* __restrict__ w2h,
    const float* __restrict__ b2, const int* __restrict__ src,
    const int* __restrict__ dst, float* __restrict__ m)
{
    __shared__ float s_x[EPB * SXS];
    __shared__ int s_dst[EPB];
    const int t = threadIdx.x;
    const int base = blockIdx.x * EPB;
    for (int i = t; i < EPB * 64; i += 256){
        int el = i >> 6, f = i & 63;
        int e = base + el;
        float v = 0.f;
        if (e < EE) v = h[(size_t)src[e] * 64 + f];
        s_x[el * SXS + f] = v;
    }
    if (t < EPB){
        int e = base + t;
        s_dst[t] = (e < EE) ? dst[e] : -1;
    }
    __syncthreads();

    const int lane = t & 63;
    const int wid = t >> 6;
    const int r16 = lane & 15;
    const int kg = lane >> 4;
    const int we = wid * 64;                 // wave's local edge base

    // A fragments (hi and lo) live in regs for the whole d-loop: 128 VGPR
    f16x8 ah[4][4], al[4][4];
    #pragma unroll
    for (int mt = 0; mt < 4; mt++){
        int e = base + we + mt * 16 + r16;
        #pragma unroll
        for (int ks = 0; ks < 4; ks++){
            if (e < EE){
                ah[mt][ks] = *(const f16x8*)(hidh + (size_t)e * 128 + ks * 32 + kg * 8);
                al[mt][ks] = *(const f16x8*)(hidl + (size_t)e * 128 + ks * 32 + kg * 8);
            } else {
                f16x8 z = {0,0,0,0,0,0,0,0};
                ah[mt][ks] = z; al[mt][ks] = z;
            }
        }
    }

    f32x4 msg[4][4];                         // [mt][ft]: 64 VGPR
    #pragma unroll
    for (int a = 0; a < 4; a++)
        #pragma unroll
        for (int b = 0; b < 4; b++){
            f32x4 z = {0.f, 0.f, 0.f, 0.f};
            msg[a][b] = z;
        }

    // per-lane B base: col = d*64 + ft*16 + r16 -> addr = base + d*8192 + ft*2048
    const f16* __restrict__ bbase = w2h + (size_t)r16 * 128 + kg * 8;
    const float* __restrict__ b2base = b2 + r16;

    for (int d = 0; d < 64; d++){
        f32x4 xv[4];
        #pragma unroll
        for (int mt = 0; mt < 4; mt++)
            #pragma unroll
            for (int r = 0; r < 4; r++)
                xv[mt][r] = s_x[(we + mt * 16 + kg * 4 + r) * SXS + d];
        const f16* bd = bbase + d * 8192;
        // batch all 16 B loads before the MFMA block
        f16x8 bf[4][4];
        #pragma unroll
        for (int ft = 0; ft < 4; ft++){
            bf[ft][0] = *(const f16x8*)(bd + ft * 2048);
            bf[ft][1] = *(const f16x8*)(bd + ft * 2048 + 32);
            bf[ft][2] = *(const f16x8*)(bd + ft * 2048 + 64);
            bf[ft][3] = *(const f16x8*)(bd + ft * 2048 + 96);
        }
        const float* b2d = b2base + d * 64;
        #pragma unroll
        for (int ft = 0; ft < 4; ft++){
            float b2v = b2d[ft * 16];
            #pragma unroll
            for (int mt = 0; mt < 4; mt++){
                f32x4 acc = {b2v, b2v, b2v, b2v};
                acc = __builtin_amdgcn_mfma_f32_16x16x32_f16(ah[mt][0], bf[ft][0], acc, 0, 0, 0);
                acc = __builtin_amdgcn_mfma_f32_16x16x32_f16(ah[mt][1], bf[ft][1], acc, 0, 0, 0);
                acc = __builtin_amdgcn_mfma_f32_16x16x32_f16(ah[mt][2], bf[ft][2], acc, 0, 0, 0);
                acc = __builtin_amdgcn_mfma_f32_16x16x32_f16(ah[mt][3], bf[ft][3], acc, 0, 0, 0);
                acc = __builtin_amdgcn_mfma_f32_16x16x32_f16(al[mt][0], bf[ft][0], acc, 0, 0, 0);
                acc = __builtin_amdgcn_mfma_f32_16x16x32_f16(al[mt][1], bf[ft][1], acc, 0, 0, 0);
                acc = __builtin_amdgcn_mfma_f32_16x16x32_f16(al[mt][2], bf[ft][2], acc, 0, 0, 0);
                acc = __builtin_amdgcn_mfma_f32_16x16x32_f16(al[mt][3], bf[ft][3], acc, 0, 0, 0);
                msg[mt][ft] = xv[mt] * acc + msg[mt][ft];
            }
        }
    }
    // scatter-add into m[dst[e], f]
    #pragma unroll
    for (int mt = 0; mt < 4; mt++){
        #pragma unroll
        for (int r = 0; r < 4; r++){
            int el = we + mt * 16 + kg * 4 + r;
            int dt = s_dst[el];
            if (dt >= 0){
                #pragma unroll
                for (int ft = 0; ft < 4; ft++)
                    atomicAdd(&m[(size_t)dt * 64 + ft * 16 + r16], msg[mt][ft][r]);
            }
        }
    }
}

// ---------------- fused GRU: gi/gh never hit HBM; gates applied in-kernel ----
// block = 128 nodes, 256 threads: thread = (node nl, f-half fh of 32).
// Each thread computes r/z/n slabs of BOTH gi and gh for its 32 f's (96 regs),
// then h' = (1-z)*n + z*h. Blocks touch only their own h rows -> in-place safe.
__global__ __launch_bounds__(256) void gru_fused_kernel(
    const float* __restrict__ m, const float* __restrict__ wTs,
    const float* __restrict__ effb, const float* __restrict__ bhh,
    float* __restrict__ h)
{
    const int n0 = blockIdx.x * 128;
    const int t = threadIdx.x;
    const int nl = t & 127;
    const int fh = t >> 7;
    __shared__ float s_m[128][65];
    __shared__ float s_h[128][65];
    for (int i = t; i < 128 * 64; i += 256){
        int nn = i >> 6, d = i & 63;
        int n = n0 + nn;
        s_m[nn][d] = (n < NN) ? m[(size_t)n * 64 + d] : 0.f;
        s_h[nn][d] = (n < NN) ? h[(size_t)n * 64 + d] : 0.f;
    }
    __syncthreads();
    int n = n0 + nl;
    if (n >= NN) return;
    for (int fc = 0; fc < 2; fc++){
        int f0 = fh * 32 + fc * 16;
        float gi3[3][16], gh3[3][16];
        #pragma unroll
        for (int p = 0; p < 3; p++)
            #pragma unroll
            for (int j = 0; j < 16; j++){
                gi3[p][j] = effb[p * 64 + f0 + j];
                gh3[p][j] = bhh[p * 64 + f0 + j];
            }
        for (int d = 0; d < 64; d++){
            float xm = s_m[nl][d], xh = s_h[nl][d];
            const float* wi = wTs + d * 192 + f0;
            const float* wh = wTs + 12288 + d * 192 + f0;
            #pragma unroll
            for (int p = 0; p < 3; p++){
                #pragma unroll
                for (int j = 0; j < 16; j++){
                    gi3[p][j] = fmaf(xm, wi[p * 64 + j], gi3[p][j]);
                    gh3[p][j] = fmaf(xh, wh[p * 64 + j], gh3[p][j]);
                }
            }
        }
        #pragma unroll
        for (int j = 0; j < 16; j++){
            float r = sigmoidf_(gi3[0][j] + gh3[0][j]);
            float z = sigmoidf_(gi3[1][j] + gh3[1][j]);
            float nv = tanhf_(gi3[2][j] + r * gh3[2][j]);
            int f = f0 + j;
            h[(size_t)n * 64 + f] = (1.f - z) * nv + z * s_h[nl][f];
        }
    }
}

// ---------------- Set2Set + final projection: one block per graph ------------
__global__ __launch_bounds__(256) void set2set_kernel(
    const float* __restrict__ out, const int* __restrict__ offs,
    const float* __restrict__ lsT, const float* __restrict__ ls_bih,
    const float* __restrict__ ls_bhh, const float* __restrict__ lin3T,
    const float* __restrict__ lin3_b, const float* __restrict__ pred_w,
    const float* __restrict__ pred_b, float* __restrict__ e_ws,
    float* __restrict__ pred_out)
{
    int g = blockIdx.x;
    int t = threadIdx.x;
    int ln = t >> 6, d = t & 63;
    __shared__ float s_qstar[128], s_h[3][64], s_c[3][64], s_g[256];
    __shared__ float s_r[4][64], s_red[4], s_wsum[4], s_y[128];
    if (t < 128) s_qstar[t] = 0.f;
    if (t < 192){ s_h[t / 64][t % 64] = 0.f; s_c[t / 64][t % 64] = 0.f; }
    int ns = offs[g], ne = offs[g + 1];
    __syncthreads();

    for (int it = 0; it < 6; it++){
        for (int l = 0; l < 3; l++){
            const float* xv = (l == 0) ? s_qstar : s_h[l - 1];
            int xdim = (l == 0) ? 128 : 64;
            const float* wxT = lsT + ((l == 0) ? 0 : (32768 + (l - 1) * 16384));
            const float* whT = lsT + 65536 + l * 16384;
            float acc = ls_bih[l * 256 + t] + ls_bhh[l * 256 + t];
            for (int j = 0; j < xdim; j++) acc = fmaf(xv[j], wxT[j * 256 + t], acc);
            #pragma unroll 4
            for (int j = 0; j < 64; j++) acc = fmaf(s_h[l][j], whT[j * 256 + t], acc);
            __syncthreads();
            s_g[t] = acc;
            __syncthreads();
            if (t < 64){
                float iv = s_g[t], fv = s_g[64 + t], gv = s_g[128 + t], ov = s_g[192 + t];
                float c2 = sigmoidf_(fv) * s_c[l][t] + sigmoidf_(iv) * tanhf_(gv);
                float h2 = sigmoidf_(ov) * tanhf_(c2);
                s_c[l][t] = c2; s_h[l][t] = h2;
            }
            __syncthreads();
        }
        float wmax = -3.4e38f;
        for (int n = ns + ln; n < ne; n += 4){
            float p = out[(size_t)n * 64 + d] * s_h[2][d];
            #pragma unroll
            for (int o = 1; o < 64; o <<= 1) p += __shfl_xor(p, o);
            if (d == 0) e_ws[n] = p;
            wmax = fmaxf(wmax, p);
        }
        if (d == 0) s_red[ln] = wmax;
        __syncthreads();
        float gmax = fmaxf(fmaxf(s_red[0], s_red[1]), fmaxf(s_red[2], s_red[3]));
        float wsum = 0.f, racc = 0.f;
        for (int n = ns + ln; n < ne; n += 4){
            float w = __expf(e_ws[n] - gmax);
            wsum += w;
            racc = fmaf(w, out[(size_t)n * 64 + d], racc);
        }
        s_r[ln][d] = racc;
        if (d == 0) s_wsum[ln] = wsum;
        __syncthreads();
        if (t < 64){
            float gsum = s_wsum[0] + s_wsum[1] + s_wsum[2] + s_wsum[3];
            float ro = s_r[0][t] + s_r[1][t] + s_r[2][t] + s_r[3][t];
            ro = (gsum > 0.f) ? ro / gsum : 0.f;
            s_qstar[t] = s_h[2][t];
            s_qstar[64 + t] = ro;
        }
        __syncthreads();
    }
    if (t < 128){
        float acc = lin3_b[t];
        #pragma unroll 4
        for (int i = 0; i < 128; i++) acc = fmaf(s_qstar[i], lin3T[i * 128 + t], acc);
        s_y[t] = fmaxf(acc, 0.f);
    }
    __syncthreads();
    if (t < 64){
        float p = s_y[t] * pred_w[t] + s_y[64 + t] * pred_w[64 + t];
        #pragma unroll
        for (int o = 1; o < 64; o <<= 1) p += __shfl_xor(p, o);
        if (t == 0) pred_out[g] = p + pred_b[0];
    }
}

extern "C" void kernel_launch(void* const* d_in, const int* in_sizes, int n_in,
                              void* d_out, int out_size, void* d_ws, size_t ws_size,
                              hipStream_t stream)
{
    (void)in_sizes; (void)n_in; (void)out_size; (void)ws_size;
    const float* n_feat  = (const float*)d_in[0];
    const float* e_feat  = (const float*)d_in[1];
    const int*   src     = (const int*)d_in[2];
    const int*   dst     = (const int*)d_in[3];
    const int*   node_graph = (const int*)d_in[4];
    const float* lin0_w  = (const float*)d_in[6];
    const float* lin0_b  = (const float*)d_in[7];
    const float* en_w1   = (const float*)d_in[8];
    const float* en_b1   = (const float*)d_in[9];
    const float* en_w2   = (const float*)d_in[10];
    const float* en_b2   = (const float*)d_in[11];
    const float* conv_b  = (const float*)d_in[12];
    const float* gru_wih = (const float*)d_in[13];
    const float* gru_whh = (const float*)d_in[14];
    const float* gru_bih = (const float*)d_in[15];
    const float* gru_bhh = (const float*)d_in[16];
    const float* ls_wih0 = (const float*)d_in[17];
    const float* ls_wih12= (const float*)d_in[18];
    const float* ls_whh  = (const float*)d_in[19];
    const float* ls_bih  = (const float*)d_in[20];
    const float* ls_bhh  = (const float*)d_in[21];
    const float* lin3_w  = (const float*)d_in[22];
    const float* lin3_b  = (const float*)d_in[23];
    const float* pred_w  = (const float*)d_in[24];
    const float* pred_b  = (const float*)d_in[25];

    float* h = (float*)d_out;                       // N x 64 (also "out")
    float* pred_out = (float*)d_out + (size_t)NN * 64;

    char* ws = (char*)d_ws;
    f16*   hidh  = (f16*)(ws + 0);                  // 25,600,000
    f16*   hidl  = (f16*)(ws + 25600000);           // 25,600,000
    float* m     = (float*)(ws + 51200000);         // 10,240,000
    f16*   w2h   = (f16*)(ws + 61440000);           //  1,048,576
    float* wTs   = (float*)(ws + 62488576);         //     98,304
    float* lsT   = (float*)(ws + 62586880);         //    458,752
    float* lin3T = (float*)(ws + 63045632);         //     65,536
    float* effb  = (float*)(ws + 63111168);         //        768
    float* e_ws  = (float*)(ws + 63111936);         //    160,000
    int*   offs  = (int*)(ws + 63271936);           //      1,028

    prep_kernel<<<2658, 256, 0, stream>>>(en_w2, w2h, gru_wih, gru_whh, wTs,
                                          ls_wih0, ls_wih12, ls_whh, lsT,
                                          lin3_w, lin3T, gru_bih, conv_b, effb,
                                          node_graph, offs);
    lin0_kernel<<<(NN * 64) / 256, 256, 0, stream>>>(n_feat, lin0_w, lin0_b, h);
    edge_hidden_kernel<<<(EE * 128) / 256, 256, 0, stream>>>(e_feat, en_w1, en_b1, hidh, hidl);

    for (int step = 0; step < 6; step++){
        hipMemsetAsync(m, 0, (size_t)NN * 64 * sizeof(float), stream);
        msg_fused_kernel<<<(EE + EPB - 1) / EPB, 256, 0, stream>>>(h, hidh, hidl, w2h,
                                                                   en_b2, src, dst, m);
        gru_fused_kernel<<<(NN + 127) / 128, 256, 0, stream>>>(m, wTs, effb, gru_bhh, h);
    }

    set2set_kernel<<<BB, 256, 0, stream>>>(h, offs, lsT, ls_bih, ls_bhh,
                                           lin3T, lin3_b, pred_w, pred_b,
                                           e_ws, pred_out);
}

// Round 9
// 3323.957 us; speedup vs baseline: 1.1445x; 1.0203x over previous
//
#include <hip/hip_runtime.h>

typedef unsigned short u16;
typedef unsigned int u32;
typedef _Float16 f16;
typedef __attribute__((ext_vector_type(8))) _Float16 f16x8;
typedef __attribute__((ext_vector_type(4))) float f32x4;

#define NN 40000
#define EE 100000
#define DD 64
#define BB 256
#define SXS 68   // padded LDS stride: kg-groups land 16 banks apart (2-way = free)
#define EPB 256  // edges per block (4 waves x 64 edges; K split over time)

__device__ inline float sigmoidf_(float x){
    return 1.f / (1.f + __expf(-x));
}
__device__ inline float tanhf_(float x){
    x = fmaxf(fminf(x, 15.f), -15.f);
    float e = __expf(2.f * x);
    return (e - 1.f) / (e + 1.f);
}

// ---------------- prep: transposes, f16 convert, eff bias, offsets -----------
__global__ __launch_bounds__(256) void prep_kernel(
    const float* __restrict__ en_w2, f16* __restrict__ w2h,
    const float* __restrict__ gru_wih, const float* __restrict__ gru_whh,
    float* __restrict__ wTs,
    const float* __restrict__ ls_wih0, const float* __restrict__ ls_wih12,
    const float* __restrict__ ls_whh, float* __restrict__ lsT,
    const float* __restrict__ lin3_w, float* __restrict__ lin3T,
    const float* __restrict__ gru_bih, const float* __restrict__ conv_b,
    float* __restrict__ effb,
    const int* __restrict__ node_graph, int* __restrict__ offs)
{
    int i = blockIdx.x * 256 + threadIdx.x;
    if (i < 524288){
        w2h[i] = (f16)en_w2[i];
        return;
    }
    i -= 524288;
    if (i < 24576){
        int which = i / 12288, r = i % 12288;
        int d = r / 192, g = r % 192;
        const float* W = which ? gru_whh : gru_wih;
        wTs[which * 12288 + d * 192 + g] = W[g * 64 + d];
        return;
    }
    i -= 24576;
    if (i < 114688){
        float v;
        if (i < 32768){
            int d = i >> 8, g = i & 255;
            v = ls_wih0[g * 128 + d];
        } else if (i < 65536){
            int j = i - 32768;
            int l = j >> 14, r = j & 16383;
            int d = r >> 8, g = r & 255;
            v = ls_wih12[l * 16384 + g * 64 + d];
        } else {
            int j = i - 65536;
            int l = j >> 14, r = j & 16383;
            int d = r >> 8, g = r & 255;
            v = ls_whh[l * 16384 + g * 64 + d];
        }
        lsT[i] = v;
        return;
    }
    i -= 114688;
    if (i < 16384){
        int ii = i >> 7, jj = i & 127;
        lin3T[i] = lin3_w[jj * 128 + ii];
        return;
    }
    i -= 16384;
    if (i < 192){
        float b = gru_bih[i];
        #pragma unroll
        for (int d = 0; d < 64; d++) b += gru_wih[i * 64 + d] * conv_b[d];
        effb[i] = b;
        return;
    }
    i -= 192;
    if (i <= 256){
        int lo = 0, hi = NN;
        while (lo < hi){
            int mid = (lo + hi) >> 1;
            if (node_graph[mid] < i) lo = mid + 1; else hi = mid;
        }
        offs[i] = lo;
        return;
    }
}

// ---------------- lin0: out = n_feat @ lin0_w^T + b  (writes h in d_out) -----
__global__ __launch_bounds__(256) void lin0_kernel(
    const float* __restrict__ nf, const float* __restrict__ w,
    const float* __restrict__ b, float* __restrict__ out)
{
    int tid = blockIdx.x * 256 + threadIdx.x;
    int n = tid >> 6, d = tid & 63;
    if (n >= NN) return;
    float acc = b[d];
    const float* nr = nf + (size_t)n * 23;
    const float* wr = w + d * 23;
    #pragma unroll
    for (int j = 0; j < 23; j++) acc = fmaf(nr[j], wr[j], acc);
    out[(size_t)n * 64 + d] = acc;
}

// ---------------- edge hidden: relu(e_feat @ w1^T + b1) -> f16 hi/lo ---------
__global__ __launch_bounds__(256) void edge_hidden_kernel(
    const float* __restrict__ ef, const float* __restrict__ w1,
    const float* __restrict__ b1, f16* __restrict__ hidh, f16* __restrict__ hidl)
{
    int tid = blockIdx.x * 256 + threadIdx.x;
    int e = tid >> 7, k = tid & 127;
    if (e >= EE) return;
    float acc = b1[k];
    const float* er = ef + (size_t)e * 19;
    const float* wr = w1 + k * 19;
    #pragma unroll
    for (int j = 0; j < 19; j++) acc = fmaf(er[j], wr[j], acc);
    acc = fmaxf(acc, 0.f);
    f16 hi = (f16)acc;
    f16 lo = (f16)(acc - (float)hi);
    hidh[(size_t)e * 128 + k] = hi;
    hidl[(size_t)e * 128 + k] = lo;
}

// ---------------- fused msg: ew tile stays in MFMA accs, never stored --------
// msg[e,f] = sum_d x[e,d] * ( sum_k u[e,k]*W2[d*64+f,k] + b2[d*64+f] )
// block = 256 edges (4 waves x 64 edges). K=128 split over TIME (two d-loop
// passes, k-half each): per-pass regs A hi+lo 64 + msg 64 + B dbuf 16 + xv 16
// ~ 180 VGPR -> 2 waves/SIMD, everything register-resident by construction.
// B loads software-pipelined across the (d,ft) chain via named double buffers.
// b2 C-in only on half 0; msg accumulates across halves (linear in k).
__global__ __launch_bounds__(256)
__attribute__((amdgpu_waves_per_eu(1, 2)))
void msg_fused_kernel(
    const float* __restrict__ h, const f16* __restrict__ hidh,
    const f16* __restrict__ hidl, const f16* __restrict__ w2h,
    const float* __restrict__ b2, const int* __restrict__ src,
    const int* __restrict__ dst, float* __restrict__ m)
{
    __shared__ float s_x[EPB * SXS];
    __shared__ int s_dst[EPB];
    const int t = threadIdx.x;
    const int base = blockIdx.x * EPB;
    for (int i = t; i < EPB * 64; i += 256){
        int el = i >> 6, f = i & 63;
        int e = base + el;
        float v = 0.f;
        if (e < EE) v = h[(size_t)src[e] * 64 + f];
        s_x[el * SXS + f] = v;
    }
    if (t < EPB){
        int e = base + t;
        s_dst[t] = (e < EE) ? dst[e] : -1;
    }
    __syncthreads();

    const int lane = t & 63;
    const int wid = t >> 6;
    const int r16 = lane & 15;
    const int kg = lane >> 4;
    const int we = wid * 64;                 // wave's local edge base

    f32x4 msg[4][4];                         // [mt][ft]: 64 VGPR, lives both halves
    #pragma unroll
    for (int a = 0; a < 4; a++)
        #pragma unroll
        for (int b = 0; b < 4; b++){
            f32x4 z = {0.f, 0.f, 0.f, 0.f};
            msg[a][b] = z;
        }

    const f16* __restrict__ bbase = w2h + (size_t)r16 * 128 + kg * 8;
    const float* __restrict__ b2base = b2 + r16;

    #pragma unroll
    for (int half = 0; half < 2; half++){
        // A fragments (hi+lo) for this k-half: 8 frags = 64 VGPR
        f16x8 ah[4][2], al[4][2];
        #pragma unroll
        for (int mt = 0; mt < 4; mt++){
            int e = base + we + mt * 16 + r16;
            #pragma unroll
            for (int ks = 0; ks < 2; ks++){
                int koff = half * 64 + ks * 32 + kg * 8;
                if (e < EE){
                    ah[mt][ks] = *(const f16x8*)(hidh + (size_t)e * 128 + koff);
                    al[mt][ks] = *(const f16x8*)(hidl + (size_t)e * 128 + koff);
                } else {
                    f16x8 z = {0,0,0,0,0,0,0,0};
                    ah[mt][ks] = z; al[mt][ks] = z;
                }
            }
        }

        const f16* __restrict__ bh2 = bbase + half * 64;
        // software-pipelined B: named double buffers (static regs, no scratch)
        f16x8 bA0, bA1, bB0, bB1;
        float b2A = 0.f, b2B = 0.f;
        bA0 = *(const f16x8*)(bh2);
        bA1 = *(const f16x8*)(bh2 + 32);
        if (half == 0) b2A = b2base[0];

#define COMPQ(FT, B0, B1, B2V)                                                   \
        {                                                                        \
            _Pragma("unroll")                                                    \
            for (int mt = 0; mt < 4; mt++){                                      \
                f32x4 acc = {B2V, B2V, B2V, B2V};                                \
                acc = __builtin_amdgcn_mfma_f32_16x16x32_f16(ah[mt][0], B0, acc, 0, 0, 0); \
                acc = __builtin_amdgcn_mfma_f32_16x16x32_f16(ah[mt][1], B1, acc, 0, 0, 0); \
                acc = __builtin_amdgcn_mfma_f32_16x16x32_f16(al[mt][0], B0, acc, 0, 0, 0); \
                acc = __builtin_amdgcn_mfma_f32_16x16x32_f16(al[mt][1], B1, acc, 0, 0, 0); \
                msg[mt][FT] = xv[mt] * acc + msg[mt][FT];                        \
            }                                                                    \
        }

        for (int d = 0; d < 64; d++){
            f32x4 xv[4];
            #pragma unroll
            for (int mt = 0; mt < 4; mt++)
                #pragma unroll
                for (int r = 0; r < 4; r++)
                    xv[mt][r] = s_x[(we + mt * 16 + kg * 4 + r) * SXS + d];
            const f16* bd = bh2 + d * 8192;
            // ft0: prefetch (d,1)->B, compute (d,0) from A
            bB0 = *(const f16x8*)(bd + 2048);
            bB1 = *(const f16x8*)(bd + 2048 + 32);
            if (half == 0) b2B = b2base[d * 64 + 16];
            COMPQ(0, bA0, bA1, b2A);
            // ft1: prefetch (d,2)->A, compute (d,1) from B
            bA0 = *(const f16x8*)(bd + 4096);
            bA1 = *(const f16x8*)(bd + 4096 + 32);
            if (half == 0) b2A = b2base[d * 64 + 32];
            COMPQ(1, bB0, bB1, b2B);
            // ft2: prefetch (d,3)->B, compute (d,2) from A
            bB0 = *(const f16x8*)(bd + 6144);
            bB1 = *(const f16x8*)(bd + 6144 + 32);
            if (half == 0) b2B = b2base[d * 64 + 48];
            COMPQ(2, bA0, bA1, b2A);
            // ft3: prefetch (d+1,0)->A, compute (d,3) from B
            int dn = (d < 63) ? d + 1 : 63;
            bA0 = *(const f16x8*)(bh2 + dn * 8192);
            bA1 = *(const f16x8*)(bh2 + dn * 8192 + 32);
            if (half == 0) b2A = b2base[dn * 64];
            COMPQ(3, bB0, bB1, b2B);
        }
#undef COMPQ
    }

    // scatter-add into m[dst[e], f]
    #pragma unroll
    for (int mt = 0; mt < 4; mt++){
        #pragma unroll
        for (int r = 0; r < 4; r++){
            int el = we + mt * 16 + kg * 4 + r;
            int dt = s_dst[el];
            if (dt >= 0){
                #pragma unroll
                for (int ft = 0; ft < 4; ft++)
                    atomicAdd(&m[(size_t)dt * 64 + ft * 16 + r16], msg[mt][ft][r]);
            }
        }
    }
}

// ---------------- GRU GEMM: G[n,g] = bias[g] + sum_d X[n,d]*wT[d,g], g<192 ---
__global__ __launch_bounds__(128) void gru_gemm_kernel(
    const float* __restrict__ m, const float* __restrict__ h,
    const float* __restrict__ wTs, const float* __restrict__ effb,
    const float* __restrict__ bhh,
    float* __restrict__ gi, float* __restrict__ gh)
{
    const int which = blockIdx.y;
    const float* __restrict__ X = which ? h : m;
    const float* __restrict__ wT = wTs + which * (64 * 192);
    const float* __restrict__ bias = which ? bhh : effb;
    float* __restrict__ G = which ? gh : gi;
    const int n0 = blockIdx.x * 128;
    const int t = threadIdx.x;
    __shared__ float s_x[128][65];
    __shared__ float s_b[128][17];
    for (int i = t; i < 128 * 64; i += 128){
        int nn = i >> 6, d = i & 63;
        int n = n0 + nn;
        s_x[nn][d] = (n < NN) ? X[(size_t)n * 64 + d] : 0.f;
    }
    __syncthreads();
    for (int gc = 0; gc < 12; gc++){
        float acc[16];
        #pragma unroll
        for (int j = 0; j < 16; j++) acc[j] = bias[gc * 16 + j];
        #pragma unroll 4
        for (int d = 0; d < 64; d++){
            float xv = s_x[t][d];
            const float* wr = wT + d * 192 + gc * 16;
            #pragma unroll
            for (int j = 0; j < 16; j++) acc[j] = fmaf(xv, wr[j], acc[j]);
        }
        #pragma unroll
        for (int j = 0; j < 16; j++) s_b[t][j] = acc[j];
        __syncthreads();
        for (int i = t; i < 128 * 16; i += 128){
            int nn = i >> 4, j = i & 15;
            int n = n0 + nn;
            if (n < NN) G[(size_t)n * 192 + gc * 16 + j] = s_b[nn][j];
        }
        __syncthreads();
    }
}

// ---------------- GRU gates: h' = (1-z)*n + z*h --------------------------
__global__ __launch_bounds__(256) void gru_gate_kernel(
    const float* __restrict__ gi, const float* __restrict__ gh,
    float* __restrict__ h)
{
    int tid = blockIdx.x * 256 + threadIdx.x;
    int n = tid >> 6, f = tid & 63;
    if (n >= NN) return;
    size_t b = (size_t)n * 192;
    float ir = gi[b + f], iz = gi[b + 64 + f], inn = gi[b + 128 + f];
    float hr = gh[b + f], hz = gh[b + 64 + f], hn = gh[b + 128 + f];
    float r = sigmoidf_(ir + hr);
    float z = sigmoidf_(iz + hz);
    float nv = tanhf_(inn + r * hn);
    size_t hb = (size_t)n * 64 + f;
    float hv = h[hb];
    h[hb] = (1.f - z) * nv + z * hv;
}

// ---------------- Set2Set + final projection: one block per graph ------------
__global__ __launch_bounds__(256) void set2set_kernel(
    const float* __restrict__ out, const int* __restrict__ offs,
    const float* __restrict__ lsT, const float* __restrict__ ls_bih,
    const float* __restrict__ ls_bhh, const float* __restrict__ lin3T,
    const float* __restrict__ lin3_b, const float* __restrict__ pred_w,
    const float* __restrict__ pred_b, float* __restrict__ e_ws,
    float* __restrict__ pred_out)
{
    int g = blockIdx.x;
    int t = threadIdx.x;
    int ln = t >> 6, d = t & 63;
    __shared__ float s_qstar[128], s_h[3][64], s_c[3][64], s_g[256];
    __shared__ float s_r[4][64], s_red[4], s_wsum[4], s_y[128];
    if (t < 128) s_qstar[t] = 0.f;
    if (t < 192){ s_h[t / 64][t % 64] = 0.f; s_c[t / 64][t % 64] = 0.f; }
    int ns = offs[g], ne = offs[g + 1];
    __syncthreads();

    for (int it = 0; it < 6; it++){
        for (int l = 0; l < 3; l++){
            const float* xv = (l == 0) ? s_qstar : s_h[l - 1];
            int xdim = (l == 0) ? 128 : 64;
            const float* wxT = lsT + ((l == 0) ? 0 : (32768 + (l - 1) * 16384));
            const float* whT = lsT + 65536 + l * 16384;
            float acc = ls_bih[l * 256 + t] + ls_bhh[l * 256 + t];
            for (int j = 0; j < xdim; j++) acc = fmaf(xv[j], wxT[j * 256 + t], acc);
            #pragma unroll 4
            for (int j = 0; j < 64; j++) acc = fmaf(s_h[l][j], whT[j * 256 + t], acc);
            __syncthreads();
            s_g[t] = acc;
            __syncthreads();
            if (t < 64){
                float iv = s_g[t], fv = s_g[64 + t], gv = s_g[128 + t], ov = s_g[192 + t];
                float c2 = sigmoidf_(fv) * s_c[l][t] + sigmoidf_(iv) * tanhf_(gv);
                float h2 = sigmoidf_(ov) * tanhf_(c2);
                s_c[l][t] = c2; s_h[l][t] = h2;
            }
            __syncthreads();
        }
        float wmax = -3.4e38f;
        for (int n = ns + ln; n < ne; n += 4){
            float p = out[(size_t)n * 64 + d] * s_h[2][d];
            #pragma unroll
            for (int o = 1; o < 64; o <<= 1) p += __shfl_xor(p, o);
            if (d == 0) e_ws[n] = p;
            wmax = fmaxf(wmax, p);
        }
        if (d == 0) s_red[ln] = wmax;
        __syncthreads();
        float gmax = fmaxf(fmaxf(s_red[0], s_red[1]), fmaxf(s_red[2], s_red[3]));
        float wsum = 0.f, racc = 0.f;
        for (int n = ns + ln; n < ne; n += 4){
            float w = __expf(e_ws[n] - gmax);
            wsum += w;
            racc = fmaf(w, out[(size_t)n * 64 + d], racc);
        }
        s_r[ln][d] = racc;
        if (d == 0) s_wsum[ln] = wsum;
        __syncthreads();
        if (t < 64){
            float gsum = s_wsum[0] + s_wsum[1] + s_wsum[2] + s_wsum[3];
            float ro = s_r[0][t] + s_r[1][t] + s_r[2][t] + s_r[3][t];
            ro = (gsum > 0.f) ? ro / gsum : 0.f;
            s_qstar[t] = s_h[2][t];
            s_qstar[64 + t] = ro;
        }
        __syncthreads();
    }
    if (t < 128){
        float acc = lin3_b[t];
        #pragma unroll 4
        for (int i = 0; i < 128; i++) acc = fmaf(s_qstar[i], lin3T[i * 128 + t], acc);
        s_y[t] = fmaxf(acc, 0.f);
    }
    __syncthreads();
    if (t < 64){
        float p = s_y[t] * pred_w[t] + s_y[64 + t] * pred_w[64 + t];
        #pragma unroll
        for (int o = 1; o < 64; o <<= 1) p += __shfl_xor(p, o);
        if (t == 0) pred_out[g] = p + pred_b[0];
    }
}

extern "C" void kernel_launch(void* const* d_in, const int* in_sizes, int n_in,
                              void* d_out, int out_size, void* d_ws, size_t ws_size,
                              hipStream_t stream)
{
    (void)in_sizes; (void)n_in; (void)out_size; (void)ws_size;
    const float* n_feat  = (const float*)d_in[0];
    const float* e_feat  = (const float*)d_in[1];
    const int*   src     = (const int*)d_in[2];
    const int*   dst     = (const int*)d_in[3];
    const int*   node_graph = (const int*)d_in[4];
    const float* lin0_w  = (const float*)d_in[6];
    const float* lin0_b  = (const float*)d_in[7];
    const float* en_w1   = (const float*)d_in[8];
    const float* en_b1   = (const float*)d_in[9];
    const float* en_w2   = (const float*)d_in[10];
    const float* en_b2   = (const float*)d_in[11];
    const float* conv_b  = (const float*)d_in[12];
    const float* gru_wih = (const float*)d_in[13];
    const float* gru_whh = (const float*)d_in[14];
    const float* gru_bih = (const float*)d_in[15];
    const float* gru_bhh = (const float*)d_in[16];
    const float* ls_wih0 = (const float*)d_in[17];
    const float* ls_wih12= (const float*)d_in[18];
    const float* ls_whh  = (const float*)d_in[19];
    const float* ls_bih  = (const float*)d_in[20];
    const float* ls_bhh  = (const float*)d_in[21];
    const float* lin3_w  = (const float*)d_in[22];
    const float* lin3_b  = (const float*)d_in[23];
    const float* pred_w  = (const float*)d_in[24];
    const float* pred_b  = (const float*)d_in[25];

    float* h = (float*)d_out;                       // N x 64 (also "out")
    float* pred_out = (float*)d_out + (size_t)NN * 64;

    char* ws = (char*)d_ws;
    f16*   hidh  = (f16*)(ws + 0);                  // 25,600,000
    f16*   hidl  = (f16*)(ws + 25600000);           // 25,600,000
    float* m     = (float*)(ws + 51200000);         // 10,240,000
    float* gi    = (float*)(ws + 61440000);         // 30,720,000
    float* gh    = (float*)(ws + 92160000);         // 30,720,000
    f16*   w2h   = (f16*)(ws + 122880000);          //  1,048,576
    float* wTs   = (float*)(ws + 123928576);        //     98,304
    float* lsT   = (float*)(ws + 124026880);        //    458,752
    float* lin3T = (float*)(ws + 124485632);        //     65,536
    float* effb  = (float*)(ws + 124551168);        //        768
    float* e_ws  = (float*)(ws + 124551936);        //    160,000
    int*   offs  = (int*)(ws + 124711936);          //      1,028

    prep_kernel<<<2658, 256, 0, stream>>>(en_w2, w2h, gru_wih, gru_whh, wTs,
                                          ls_wih0, ls_wih12, ls_whh, lsT,
                                          lin3_w, lin3T, gru_bih, conv_b, effb,
                                          node_graph, offs);
    lin0_kernel<<<(NN * 64) / 256, 256, 0, stream>>>(n_feat, lin0_w, lin0_b, h);
    edge_hidden_kernel<<<(EE * 128) / 256, 256, 0, stream>>>(e_feat, en_w1, en_b1, hidh, hidl);

    for (int step = 0; step < 6; step++){
        hipMemsetAsync(m, 0, (size_t)NN * 64 * sizeof(float), stream);
        msg_fused_kernel<<<(EE + EPB - 1) / EPB, 256, 0, stream>>>(h, hidh, hidl, w2h,
                                                                   en_b2, src, dst, m);
        dim3 gg((NN + 127) / 128, 2);
        gru_gemm_kernel<<<gg, 128, 0, stream>>>(m, h, wTs, effb, gru_bhh, gi, gh);
        gru_gate_kernel<<<(NN * 64) / 256, 256, 0, stream>>>(gi, gh, h);
    }

    set2set_kernel<<<BB, 256, 0, stream>>>(h, offs, lsT, ls_bih, ls_bhh,
                                           lin3T, lin3_b, pred_w, pred_b,
                                           e_ws, pred_out);
}

// Round 10
// 2275.820 us; speedup vs baseline: 1.6716x; 1.4606x over previous
//
#include <hip/hip_runtime.h>

typedef unsigned short u16;
typedef unsigned int u32;
typedef _Float16 f16;
typedef __attribute__((ext_vector_type(8))) _Float16 f16x8;
typedef __attribute__((ext_vector_type(4))) float f32x4;

#define NN 40000
#define EE 100000
#define DD 64
#define BB 256
#define SXS 68   // padded LDS stride: kg-groups land 16 banks apart (2-way = free)
#define EPB 128  // edges per block; 4 waves x 32 edges (mt=2), B staged via LDS

__device__ inline float sigmoidf_(float x){
    return 1.f / (1.f + __expf(-x));
}
__device__ inline float tanhf_(float x){
    x = fmaxf(fminf(x, 15.f), -15.f);
    float e = __expf(2.f * x);
    return (e - 1.f) / (e + 1.f);
}

// ---------------- prep: transposes, f16 convert, eff bias, offsets -----------
__global__ __launch_bounds__(256) void prep_kernel(
    const float* __restrict__ en_w2, f16* __restrict__ w2h,
    const float* __restrict__ gru_wih, const float* __restrict__ gru_whh,
    float* __restrict__ wTs,
    const float* __restrict__ ls_wih0, const float* __restrict__ ls_wih12,
    const float* __restrict__ ls_whh, float* __restrict__ lsT,
    const float* __restrict__ lin3_w, float* __restrict__ lin3T,
    const float* __restrict__ gru_bih, const float* __restrict__ conv_b,
    float* __restrict__ effb,
    const int* __restrict__ node_graph, int* __restrict__ offs)
{
    int i = blockIdx.x * 256 + threadIdx.x;
    if (i < 524288){
        w2h[i] = (f16)en_w2[i];
        return;
    }
    i -= 524288;
    if (i < 24576){
        int which = i / 12288, r = i % 12288;
        int d = r / 192, g = r % 192;
        const float* W = which ? gru_whh : gru_wih;
        wTs[which * 12288 + d * 192 + g] = W[g * 64 + d];
        return;
    }
    i -= 24576;
    if (i < 114688){
        float v;
        if (i < 32768){
            int d = i >> 8, g = i & 255;
            v = ls_wih0[g * 128 + d];
        } else if (i < 65536){
            int j = i - 32768;
            int l = j >> 14, r = j & 16383;
            int d = r >> 8, g = r & 255;
            v = ls_wih12[l * 16384 + g * 64 + d];
        } else {
            int j = i - 65536;
            int l = j >> 14, r = j & 16383;
            int d = r >> 8, g = r & 255;
            v = ls_whh[l * 16384 + g * 64 + d];
        }
        lsT[i] = v;
        return;
    }
    i -= 114688;
    if (i < 16384){
        int ii = i >> 7, jj = i & 127;
        lin3T[i] = lin3_w[jj * 128 + ii];
        return;
    }
    i -= 16384;
    if (i < 192){
        float b = gru_bih[i];
        #pragma unroll
        for (int d = 0; d < 64; d++) b += gru_wih[i * 64 + d] * conv_b[d];
        effb[i] = b;
        return;
    }
    i -= 192;
    if (i <= 256){
        int lo = 0, hi = NN;
        while (lo < hi){
            int mid = (lo + hi) >> 1;
            if (node_graph[mid] < i) lo = mid + 1; else hi = mid;
        }
        offs[i] = lo;
        return;
    }
}

// ---------------- lin0: out = n_feat @ lin0_w^T + b  (writes h in d_out) -----
__global__ __launch_bounds__(256) void lin0_kernel(
    const float* __restrict__ nf, const float* __restrict__ w,
    const float* __restrict__ b, float* __restrict__ out)
{
    int tid = blockIdx.x * 256 + threadIdx.x;
    int n = tid >> 6, d = tid & 63;
    if (n >= NN) return;
    float acc = b[d];
    const float* nr = nf + (size_t)n * 23;
    const float* wr = w + d * 23;
    #pragma unroll
    for (int j = 0; j < 23; j++) acc = fmaf(nr[j], wr[j], acc);
    out[(size_t)n * 64 + d] = acc;
}

// ---------------- edge hidden: relu(e_feat @ w1^T + b1) -> f16 hi/lo ---------
__global__ __launch_bounds__(256) void edge_hidden_kernel(
    const float* __restrict__ ef, const float* __restrict__ w1,
    const float* __restrict__ b1, f16* __restrict__ hidh, f16* __restrict__ hidl)
{
    int tid = blockIdx.x * 256 + threadIdx.x;
    int e = tid >> 7, k = tid & 127;
    if (e >= EE) return;
    float acc = b1[k];
    const float* er = ef + (size_t)e * 19;
    const float* wr = w1 + k * 19;
    #pragma unroll
    for (int j = 0; j < 19; j++) acc = fmaf(er[j], wr[j], acc);
    acc = fmaxf(acc, 0.f);
    f16 hi = (f16)acc;
    f16 lo = (f16)(acc - (float)hi);
    hidh[(size_t)e * 128 + k] = hi;
    hidl[(size_t)e * 128 + k] = lo;
}

// ---------------- fused msg: B staged via LDS, shared by all 4 waves ---------
// msg[e,f] = sum_d x[e,d] * ( sum_k u[e,k]*W2[d*64+f,k] + b2[d*64+f] )
// block = 128 edges, 4 waves x 32 edges (mt=2). Per-d 16KB W2 tile staged
// cooperatively into a double-buffered LDS slab (coalesced global reads,
// XOR-swizzled writes); fragment ds_reads are 2-way-conflict-free.
// Per-wave regs: A hi+lo 64 + msg 32 + B 16 + xv 8 ~ 130 -> fits the
// de-facto 128-VGPR clamp (R4-R9 evidence) with zero reloads.
// LDS f16x8-unit index for (col, j): col*16 + (j ^ (col&7)), j = ks*4+kg.
__global__ __launch_bounds__(256) void msg_fused_kernel(
    const float* __restrict__ h, const f16* __restrict__ hidh,
    const f16* __restrict__ hidl, const f16* __restrict__ w2h,
    const float* __restrict__ b2, const int* __restrict__ src,
    const int* __restrict__ dst, float* __restrict__ m)
{
    __shared__ float s_x[EPB * SXS];
    __shared__ int s_dst[EPB];
    __shared__ f16x8 s_b[2][1024];           // 2 x 16 KB B tiles
    const int t = threadIdx.x;
    const int base = blockIdx.x * EPB;
    for (int i = t; i < EPB * 64; i += 256){
        int el = i >> 6, f = i & 63;
        int e = base + el;
        float v = 0.f;
        if (e < EE) v = h[(size_t)src[e] * 64 + f];
        s_x[el * SXS + f] = v;
    }
    if (t < EPB){
        int e = base + t;
        s_dst[t] = (e < EE) ? dst[e] : -1;
    }

    const int lane = t & 63;
    const int wid = t >> 6;
    const int r16 = lane & 15;
    const int kg = lane >> 4;
    const int we = wid * 32;                 // wave's local edge base (32 edges)

    // A fragments (hi and lo), full K: 16 frags = 64 VGPR
    f16x8 ah[2][4], al[2][4];
    #pragma unroll
    for (int mt = 0; mt < 2; mt++){
        int e = base + we + mt * 16 + r16;
        #pragma unroll
        for (int ks = 0; ks < 4; ks++){
            if (e < EE){
                ah[mt][ks] = *(const f16x8*)(hidh + (size_t)e * 128 + ks * 32 + kg * 8);
                al[mt][ks] = *(const f16x8*)(hidl + (size_t)e * 128 + ks * 32 + kg * 8);
            } else {
                f16x8 z = {0,0,0,0,0,0,0,0};
                ah[mt][ks] = z; al[mt][ks] = z;
            }
        }
    }

    f32x4 msg[2][4];                         // [mt][ft]: 32 VGPR
    #pragma unroll
    for (int a = 0; a < 2; a++)
        #pragma unroll
        for (int b = 0; b < 4; b++){
            f32x4 z = {0.f, 0.f, 0.f, 0.f};
            msg[a][b] = z;
        }

    const float* __restrict__ b2base = b2 + r16;

    // stage d-tile DN into buffer BUF: 1024 chunks of 16B, 4 per thread
#define STAGE(DN, BUF)                                                       \
    {                                                                        \
        const f16* gsrc = w2h + (size_t)(DN) * 8192;                         \
        _Pragma("unroll")                                                    \
        for (int cc = 0; cc < 4; cc++){                                      \
            int c = t + cc * 256;                                            \
            int col = c >> 4, j = c & 15;                                    \
            f16x8 v = *(const f16x8*)(gsrc + c * 8);                         \
            s_b[BUF][col * 16 + (j ^ (col & 7))] = v;                        \
        }                                                                    \
    }

    STAGE(0, 0);
    __syncthreads();

    for (int d = 0; d < 64; d++){
        int cur = d & 1;
        if (d < 63) STAGE(d + 1, cur ^ 1);
        f32x4 xv[2];
        #pragma unroll
        for (int mt = 0; mt < 2; mt++)
            #pragma unroll
            for (int r = 0; r < 4; r++)
                xv[mt][r] = s_x[(we + mt * 16 + kg * 4 + r) * SXS + d];
        const float* b2d = b2base + d * 64;
        #pragma unroll
        for (int ft = 0; ft < 4; ft++){
            int col = ft * 16 + r16;
            const f16x8* bp = &s_b[cur][col * 16];
            int sw = r16 & 7;
            f16x8 bf0 = bp[(0 * 4 + kg) ^ sw];
            f16x8 bf1 = bp[(1 * 4 + kg) ^ sw];
            f16x8 bf2 = bp[(2 * 4 + kg) ^ sw];
            f16x8 bf3 = bp[(3 * 4 + kg) ^ sw];
            float b2v = b2d[ft * 16];
            #pragma unroll
            for (int mt = 0; mt < 2; mt++){
                f32x4 acc = {b2v, b2v, b2v, b2v};
                acc = __builtin_amdgcn_mfma_f32_16x16x32_f16(ah[mt][0], bf0, acc, 0, 0, 0);
                acc = __builtin_amdgcn_mfma_f32_16x16x32_f16(ah[mt][1], bf1, acc, 0, 0, 0);
                acc = __builtin_amdgcn_mfma_f32_16x16x32_f16(ah[mt][2], bf2, acc, 0, 0, 0);
                acc = __builtin_amdgcn_mfma_f32_16x16x32_f16(ah[mt][3], bf3, acc, 0, 0, 0);
                acc = __builtin_amdgcn_mfma_f32_16x16x32_f16(al[mt][0], bf0, acc, 0, 0, 0);
                acc = __builtin_amdgcn_mfma_f32_16x16x32_f16(al[mt][1], bf1, acc, 0, 0, 0);
                acc = __builtin_amdgcn_mfma_f32_16x16x32_f16(al[mt][2], bf2, acc, 0, 0, 0);
                acc = __builtin_amdgcn_mfma_f32_16x16x32_f16(al[mt][3], bf3, acc, 0, 0, 0);
                msg[mt][ft] = xv[mt] * acc + msg[mt][ft];
            }
        }
        __syncthreads();
    }
#undef STAGE

    // scatter-add into m[dst[e], f]
    #pragma unroll
    for (int mt = 0; mt < 2; mt++){
        #pragma unroll
        for (int r = 0; r < 4; r++){
            int el = we + mt * 16 + kg * 4 + r;
            int dt = s_dst[el];
            if (dt >= 0){
                #pragma unroll
                for (int ft = 0; ft < 4; ft++)
                    atomicAdd(&m[(size_t)dt * 64 + ft * 16 + r16], msg[mt][ft][r]);
            }
        }
    }
}

// ---------------- GRU GEMM: G[n,g] = bias[g] + sum_d X[n,d]*wT[d,g], g<192 ---
__global__ __launch_bounds__(128) void gru_gemm_kernel(
    const float* __restrict__ m, const float* __restrict__ h,
    const float* __restrict__ wTs, const float* __restrict__ effb,
    const float* __restrict__ bhh,
    float* __restrict__ gi, float* __restrict__ gh)
{
    const int which = blockIdx.y;
    const float* __restrict__ X = which ? h : m;
    const float* __restrict__ wT = wTs + which * (64 * 192);
    const float* __restrict__ bias = which ? bhh : effb;
    float* __restrict__ G = which ? gh : gi;
    const int n0 = blockIdx.x * 128;
    const int t = threadIdx.x;
    __shared__ float s_x[128][65];
    __shared__ float s_b[128][17];
    for (int i = t; i < 128 * 64; i += 128){
        int nn = i >> 6, d = i & 63;
        int n = n0 + nn;
        s_x[nn][d] = (n < NN) ? X[(size_t)n * 64 + d] : 0.f;
    }
    __syncthreads();
    for (int gc = 0; gc < 12; gc++){
        float acc[16];
        #pragma unroll
        for (int j = 0; j < 16; j++) acc[j] = bias[gc * 16 + j];
        #pragma unroll 4
        for (int d = 0; d < 64; d++){
            float xv = s_x[t][d];
            const float* wr = wT + d * 192 + gc * 16;
            #pragma unroll
            for (int j = 0; j < 16; j++) acc[j] = fmaf(xv, wr[j], acc[j]);
        }
        #pragma unroll
        for (int j = 0; j < 16; j++) s_b[t][j] = acc[j];
        __syncthreads();
        for (int i = t; i < 128 * 16; i += 128){
            int nn = i >> 4, j = i & 15;
            int n = n0 + nn;
            if (n < NN) G[(size_t)n * 192 + gc * 16 + j] = s_b[nn][j];
        }
        __syncthreads();
    }
}

// ---------------- GRU gates: h' = (1-z)*n + z*h --------------------------
__global__ __launch_bounds__(256) void gru_gate_kernel(
    const float* __restrict__ gi, const float* __restrict__ gh,
    float* __restrict__ h)
{
    int tid = blockIdx.x * 256 + threadIdx.x;
    int n = tid >> 6, f = tid & 63;
    if (n >= NN) return;
    size_t b = (size_t)n * 192;
    float ir = gi[b + f], iz = gi[b + 64 + f], inn = gi[b + 128 + f];
    float hr = gh[b + f], hz = gh[b + 64 + f], hn = gh[b + 128 + f];
    float r = sigmoidf_(ir + hr);
    float z = sigmoidf_(iz + hz);
    float nv = tanhf_(inn + r * hn);
    size_t hb = (size_t)n * 64 + f;
    float hv = h[hb];
    h[hb] = (1.f - z) * nv + z * hv;
}

// ---------------- Set2Set + final projection: one block per graph ------------
__global__ __launch_bounds__(256) void set2set_kernel(
    const float* __restrict__ out, const int* __restrict__ offs,
    const float* __restrict__ lsT, const float* __restrict__ ls_bih,
    const float* __restrict__ ls_bhh, const float* __restrict__ lin3T,
    const float* __restrict__ lin3_b, const float* __restrict__ pred_w,
    const float* __restrict__ pred_b, float* __restrict__ e_ws,
    float* __restrict__ pred_out)
{
    int g = blockIdx.x;
    int t = threadIdx.x;
    int ln = t >> 6, d = t & 63;
    __shared__ float s_qstar[128], s_h[3][64], s_c[3][64], s_g[256];
    __shared__ float s_r[4][64], s_red[4], s_wsum[4], s_y[128];
    if (t < 128) s_qstar[t] = 0.f;
    if (t < 192){ s_h[t / 64][t % 64] = 0.f; s_c[t / 64][t % 64] = 0.f; }
    int ns = offs[g], ne = offs[g + 1];
    __syncthreads();

    for (int it = 0; it < 6; it++){
        for (int l = 0; l < 3; l++){
            const float* xv = (l == 0) ? s_qstar : s_h[l - 1];
            int xdim = (l == 0) ? 128 : 64;
            const float* wxT = lsT + ((l == 0) ? 0 : (32768 + (l - 1) * 16384));
            const float* whT = lsT + 65536 + l * 16384;
            float acc = ls_bih[l * 256 + t] + ls_bhh[l * 256 + t];
            for (int j = 0; j < xdim; j++) acc = fmaf(xv[j], wxT[j * 256 + t], acc);
            #pragma unroll 4
            for (int j = 0; j < 64; j++) acc = fmaf(s_h[l][j], whT[j * 256 + t], acc);
            __syncthreads();
            s_g[t] = acc;
            __syncthreads();
            if (t < 64){
                float iv = s_g[t], fv = s_g[64 + t], gv = s_g[128 + t], ov = s_g[192 + t];
                float c2 = sigmoidf_(fv) * s_c[l][t] + sigmoidf_(iv) * tanhf_(gv);
                float h2 = sigmoidf_(ov) * tanhf_(c2);
                s_c[l][t] = c2; s_h[l][t] = h2;
            }
            __syncthreads();
        }
        float wmax = -3.4e38f;
        for (int n = ns + ln; n < ne; n += 4){
            float p = out[(size_t)n * 64 + d] * s_h[2][d];
            #pragma unroll
            for (int o = 1; o < 64; o <<= 1) p += __shfl_xor(p, o);
            if (d == 0) e_ws[n] = p;
            wmax = fmaxf(wmax, p);
        }
        if (d == 0) s_red[ln] = wmax;
        __syncthreads();
        float gmax = fmaxf(fmaxf(s_red[0], s_red[1]), fmaxf(s_red[2], s_red[3]));
        float wsum = 0.f, racc = 0.f;
        for (int n = ns + ln; n < ne; n += 4){
            float w = __expf(e_ws[n] - gmax);
            wsum += w;
            racc = fmaf(w, out[(size_t)n * 64 + d], racc);
        }
        s_r[ln][d] = racc;
        if (d == 0) s_wsum[ln] = wsum;
        __syncthreads();
        if (t < 64){
            float gsum = s_wsum[0] + s_wsum[1] + s_wsum[2] + s_wsum[3];
            float ro = s_r[0][t] + s_r[1][t] + s_r[2][t] + s_r[3][t];
            ro = (gsum > 0.f) ? ro / gsum : 0.f;
            s_qstar[t] = s_h[2][t];
            s_qstar[64 + t] = ro;
        }
        __syncthreads();
    }
    if (t < 128){
        float acc = lin3_b[t];
        #pragma unroll 4
        for (int i = 0; i < 128; i++) acc = fmaf(s_qstar[i], lin3T[i * 128 + t], acc);
        s_y[t] = fmaxf(acc, 0.f);
    }
    __syncthreads();
    if (t < 64){
        float p = s_y[t] * pred_w[t] + s_y[64 + t] * pred_w[64 + t];
        #pragma unroll
        for (int o = 1; o < 64; o <<= 1) p += __shfl_xor(p, o);
        if (t == 0) pred_out[g] = p + pred_b[0];
    }
}

extern "C" void kernel_launch(void* const* d_in, const int* in_sizes, int n_in,
                              void* d_out, int out_size, void* d_ws, size_t ws_size,
                              hipStream_t stream)
{
    (void)in_sizes; (void)n_in; (void)out_size; (void)ws_size;
    const float* n_feat  = (const float*)d_in[0];
    const float* e_feat  = (const float*)d_in[1];
    const int*   src     = (const int*)d_in[2];
    const int*   dst     = (const int*)d_in[3];
    const int*   node_graph = (const int*)d_in[4];
    const float* lin0_w  = (const float*)d_in[6];
    const float* lin0_b  = (const float*)d_in[7];
    const float* en_w1   = (const float*)d_in[8];
    const float* en_b1   = (const float*)d_in[9];
    const float* en_w2   = (const float*)d_in[10];
    const float* en_b2   = (const float*)d_in[11];
    const float* conv_b  = (const float*)d_in[12];
    const float* gru_wih = (const float*)d_in[13];
    const float* gru_whh = (const float*)d_in[14];
    const float* gru_bih = (const float*)d_in[15];
    const float* gru_bhh = (const float*)d_in[16];
    const float* ls_wih0 = (const float*)d_in[17];
    const float* ls_wih12= (const float*)d_in[18];
    const float* ls_whh  = (const float*)d_in[19];
    const float* ls_bih  = (const float*)d_in[20];
    const float* ls_bhh  = (const float*)d_in[21];
    const float* lin3_w  = (const float*)d_in[22];
    const float* lin3_b  = (const float*)d_in[23];
    const float* pred_w  = (const float*)d_in[24];
    const float* pred_b  = (const float*)d_in[25];

    float* h = (float*)d_out;                       // N x 64 (also "out")
    float* pred_out = (float*)d_out + (size_t)NN * 64;

    char* ws = (char*)d_ws;
    f16*   hidh  = (f16*)(ws + 0);                  // 25,600,000
    f16*   hidl  = (f16*)(ws + 25600000);           // 25,600,000
    float* m     = (float*)(ws + 51200000);         // 10,240,000
    float* gi    = (float*)(ws + 61440000);         // 30,720,000
    float* gh    = (float*)(ws + 92160000);         // 30,720,000
    f16*   w2h   = (f16*)(ws + 122880000);          //  1,048,576
    float* wTs   = (float*)(ws + 123928576);        //     98,304
    float* lsT   = (float*)(ws + 124026880);        //    458,752
    float* lin3T = (float*)(ws + 124485632);        //     65,536
    float* effb  = (float*)(ws + 124551168);        //        768
    float* e_ws  = (float*)(ws + 124551936);        //    160,000
    int*   offs  = (int*)(ws + 124711936);          //      1,028

    prep_kernel<<<2658, 256, 0, stream>>>(en_w2, w2h, gru_wih, gru_whh, wTs,
                                          ls_wih0, ls_wih12, ls_whh, lsT,
                                          lin3_w, lin3T, gru_bih, conv_b, effb,
                                          node_graph, offs);
    lin0_kernel<<<(NN * 64) / 256, 256, 0, stream>>>(n_feat, lin0_w, lin0_b, h);
    edge_hidden_kernel<<<(EE * 128) / 256, 256, 0, stream>>>(e_feat, en_w1, en_b1, hidh, hidl);

    for (int step = 0; step < 6; step++){
        hipMemsetAsync(m, 0, (size_t)NN * 64 * sizeof(float), stream);
        msg_fused_kernel<<<(EE + EPB - 1) / EPB, 256, 0, stream>>>(h, hidh, hidl, w2h,
                                                                   en_b2, src, dst, m);
        dim3 gg((NN + 127) / 128, 2);
        gru_gemm_kernel<<<gg, 128, 0, stream>>>(m, h, wTs, effb, gru_bhh, gi, gh);
        gru_gate_kernel<<<(NN * 64) / 256, 256, 0, stream>>>(gi, gh, h);
    }

    set2set_kernel<<<BB, 256, 0, stream>>>(h, offs, lsT, ls_bih, ls_bhh,
                                           lin3T, lin3_b, pred_w, pred_b,
                                           e_ws, pred_out);
}